// Round 15
// baseline (125.375 us; speedup 1.0000x reference)
//
#include <hip/hip_runtime.h>
#include <hip/hip_bf16.h>

// GraphFusion: 3-layer GNN, B=4 N=256 D=128 E=64.
// Exact algebra:
//   eh   = relu(P1_i + P2_j)            P1 = x@w_top + eb1, P2 = x@w_bot
//   mh   = relu(P3_i + eh@W2)           W2 = ew2@mw_bot (precomputed, bf16 frag-major)
//                                       P3 = x@mw_top + mb1 + eb2@mw_bot
//   s_i  = sum_j adj_ij * mh_ij         (fold adjacency BEFORE mw2)
//   msg_i= s_i@mw2 + (sum_j adj_ij)*mb2
//   x    = LN(x + u2(relu(u1(cat(x,msg)))))
// R14 base (124.7 us, replicated ±0.3) + ONE change: kB stages W2f in LDS
// (32KB/block) so the 16-iter hot loop has ZERO global loads (B-stream was
// L1-thrashing -> L2-latency-bound; ~70% stall cycles). Dead ends (confirmed
// by replication): JS=4, unroll-8 caps, P3-as-C-init.

constexpr int cB = 4, cN = 256, cD = 128, cE = 64, cL = 3, cH = 256; // cH = 2D
constexpr int RT = 4;                       // rows per kU/kP block
constexpr int JS = 2;                       // j-split factor for kB
#define LN_EPSF 1e-5f

typedef __attribute__((ext_vector_type(8))) short bf8;
typedef __attribute__((ext_vector_type(4))) float f4;

__device__ __forceinline__ ushort f2bf(float f) {  // RNE float->bf16 bits
    uint u = __float_as_uint(f);
    u += 0x7FFFu + ((u >> 16) & 1u);
    return (ushort)(u >> 16);
}

// ---- W2f[l] in MFMA B-fragment-major bf16
__global__ __launch_bounds__(256) void kW(const float* __restrict__ ew2,
                                          const float* __restrict__ eb2,
                                          const float* __restrict__ mw1,
                                          ushort* __restrict__ W2f,
                                          float* __restrict__ BS2) {
    int bx = blockIdx.x, l = bx >> 3, f0 = (bx & 7) * 8;
    int h = threadIdx.x;
    const float* ew2l = ew2 + l * cE * cE;
    const float* eb2l = eb2 + l * cE;
    const float* mbot = mw1 + l * (cD + cE) * cH + cD * cH;
    float acc[8];
#pragma unroll
    for (int f = 0; f < 8; ++f) acc[f] = 0.f;
    float bacc = 0.f;
    for (int e = 0; e < cE; ++e) {
        float m = mbot[e * cH + h];
        if (f0 == 0) bacc += eb2l[e] * m;
#pragma unroll
        for (int f = 0; f < 8; ++f) acc[f] += ew2l[(f0 + f) * cE + e] * m;
    }
    ushort* W2fl = W2f + l * cE * cH;
    int ht = h >> 4, hc = h & 15;
#pragma unroll
    for (int f = 0; f < 8; ++f) {
        int ff = f0 + f;
        int kc = ff >> 5, lg = (ff >> 3) & 3, e = ff & 7;
        W2fl[((ht * 2 + kc) * 64 + lg * 16 + hc) * 8 + e] = f2bf(acc[f]);
    }
    if (f0 == 0) BS2[l * cH + h] = bacc;
}

// ---- projection phase, 1024-thread k-split version (shared by kP and kU)
__device__ __forceinline__ void proj_1024(const float (*xs)[cD],
                                          float (*ph4)[RT][cH],
                                          float (*pm8)[RT][cD],
                                          int r0, int t,
                                          const float* __restrict__ ew1,
                                          const float* __restrict__ eb1,
                                          const float* __restrict__ mw1,
                                          const float* __restrict__ mb1,
                                          const float* __restrict__ bs2,
                                          float* __restrict__ P1,
                                          float* __restrict__ P2,
                                          float* __restrict__ P3, int nl) {
    // P3 partials: col t&255, kc=t>>8 (4-way over K=128 -> 32 iters)
    {
        int col = t & 255, kc = t >> 8;
        const float* mw1n = mw1 + nl * (cD + cE) * cH;
        float a[RT];
#pragma unroll
        for (int r = 0; r < RT; ++r) a[r] = 0.f;
        for (int k = kc * 32; k < kc * 32 + 32; ++k) {
            float w = mw1n[k * cH + col];
#pragma unroll
            for (int r = 0; r < RT; ++r) a[r] += xs[r][k] * w;
        }
#pragma unroll
        for (int r = 0; r < RT; ++r) ph4[kc][r][col] = a[r];
    }
    // P1/P2 partials: cc=t&127 (which=cc>>6,e=cc&63), kc=t>>7 (8-way -> 16 iters)
    {
        int cc = t & 127, kc = t >> 7;
        int which = cc >> 6, e = cc & 63;
        const float* ew1n = ew1 + nl * 2 * cD * cE + which * cD * cE;
        float a[RT];
#pragma unroll
        for (int r = 0; r < RT; ++r) a[r] = 0.f;
        for (int k = kc * 16; k < kc * 16 + 16; ++k) {
            float w = ew1n[k * cE + e];
#pragma unroll
            for (int r = 0; r < RT; ++r) a[r] += xs[r][k] * w;
        }
#pragma unroll
        for (int r = 0; r < RT; ++r) pm8[kc][r][cc] = a[r];
    }
    __syncthreads();
    {
        int r = t >> 8, col = t & 255;
        float v = mb1[nl * cH + col] + bs2[nl * cH + col];
#pragma unroll
        for (int kc = 0; kc < 4; ++kc) v += ph4[kc][r][col];
        P3[(r0 + r) * cH + col] = v;
    }
    if (t < 512) {
        int r = t >> 7, cc = t & 127, which = cc >> 6, e = cc & 63;
        float v = which ? 0.f : eb1[nl * cE + e];
#pragma unroll
        for (int kc = 0; kc < 8; ++kc) v += pm8[kc][r][cc];
        (which ? P2 : P1)[(r0 + r) * cE + e] = v;
    }
}

// ---- layer-0 projections, grid = B*N/RT, 1024 threads
__global__ __launch_bounds__(1024) void kP(const float* __restrict__ x,
                                           const float* __restrict__ ew1,
                                           const float* __restrict__ eb1,
                                           const float* __restrict__ mw1,
                                           const float* __restrict__ mb1,
                                           const float* __restrict__ bs2,
                                           float* __restrict__ P1,
                                           float* __restrict__ P2,
                                           float* __restrict__ P3) {
    __shared__ float xs[RT][cD];
    __shared__ float ph4[4][RT][cH];
    __shared__ float pm8[8][RT][cD];
    int r0 = blockIdx.x * RT, t = threadIdx.x;
    if (t < 512) {
        int r = t >> 7, d = t & 127;
        xs[r][d] = x[(r0 + r) * cD + d];
    }
    __syncthreads();
    proj_1024(xs, ph4, pm8, r0, t, ew1, eb1, mw1, mb1, bs2, P1, P2, P3, 0);
}

// ---- hot kernel (MFMA): block = (b,i, j-half); wave w owns j in [half*128+32w, +32)
// W2f layer slice staged in LDS: hot loop has no global loads.
__global__ __launch_bounds__(256) void kB(const float* __restrict__ P1,
                                          const float* __restrict__ P2,
                                          const float* __restrict__ P3,
                                          const float* __restrict__ adj,
                                          const ushort* __restrict__ W2f,
                                          float* __restrict__ Sp,
                                          float* __restrict__ AsumP, int l) {
    __shared__ float sP3[cH];
    __shared__ ushort sW2[cE * cH];     // 32 KB: full B-operand, frag-major
    __shared__ float sS[4][cH];
    __shared__ float sAs[4];
    int bx = blockIdx.x, bn = bx >> 1, half = bx & 1;
    int t = threadIdx.x, w = t >> 6, ln = t & 63, g = ln >> 4, c = ln & 15;
    int b = bn >> 8;
    int jw = half * 128 + w * 32;

    sP3[t] = P3[bn * cH + t];

    // stage W2f layer slice: 256 thr x 8 x 16B = 32 KB (coalesced, before barrier)
    {
        const ushort* W2l = W2f + l * cE * cH;
#pragma unroll
        for (int it = 0; it < 8; ++it) {
            int idx = (it * 256 + t) * 8;
            *(f4*)(&sW2[idx]) = *(const f4*)(&W2l[idx]);
        }
    }

    const float* adjr = adj + bn * cN + jw;
    float adjv[2][4];
    float asum = 0.f;
#pragma unroll
    for (int jt = 0; jt < 2; ++jt)
#pragma unroll
        for (int q = 0; q < 4; ++q) {
            float a = adjr[jt * 16 + g * 4 + q];
            adjv[jt][q] = a;
            asum += a;
        }
    asum += __shfl_xor(asum, 16);
    asum += __shfl_xor(asum, 32);

    const float* p1p = P1 + bn * cE;
    f4 p1lo[2], p1hi[2];
#pragma unroll
    for (int kc = 0; kc < 2; ++kc) {
        p1lo[kc] = *(const f4*)(p1p + kc * 32 + g * 8);
        p1hi[kc] = *(const f4*)(p1p + kc * 32 + g * 8 + 4);
    }

    bf8 af[2][2];
#pragma unroll
    for (int jt = 0; jt < 2; ++jt) {
        const float* p2r = P2 + (b * cN + jw + jt * 16 + c) * cE;
#pragma unroll
        for (int kc = 0; kc < 2; ++kc) {
            f4 v0 = *(const f4*)(p2r + kc * 32 + g * 8);
            f4 v1 = *(const f4*)(p2r + kc * 32 + g * 8 + 4);
            bf8 a;
#pragma unroll
            for (int e = 0; e < 4; ++e) {
                float x0 = v0[e] + p1lo[kc][e]; x0 = x0 > 0.f ? x0 : 0.f;
                float x1 = v1[e] + p1hi[kc][e]; x1 = x1 > 0.f ? x1 : 0.f;
                a[e]     = (short)f2bf(x0);
                a[e + 4] = (short)f2bf(x1);
            }
            af[jt][kc] = a;
        }
    }
    __syncthreads();   // sP3 + sW2 ready

    for (int ht = 0; ht < 16; ++ht) {
        bf8 b0 = *(const bf8*)(&sW2[((ht * 2 + 0) * 64 + ln) * 8]);
        bf8 b1 = *(const bf8*)(&sW2[((ht * 2 + 1) * 64 + ln) * 8]);
        float p3v = sP3[ht * 16 + c];
        float sp = 0.f;
#pragma unroll
        for (int jt = 0; jt < 2; ++jt) {
            f4 acc = {0.f, 0.f, 0.f, 0.f};
            acc = __builtin_amdgcn_mfma_f32_16x16x32_bf16(af[jt][0], b0, acc, 0, 0, 0);
            acc = __builtin_amdgcn_mfma_f32_16x16x32_bf16(af[jt][1], b1, acc, 0, 0, 0);
#pragma unroll
            for (int q = 0; q < 4; ++q) {
                float mh = p3v + acc[q];
                mh = mh > 0.f ? mh : 0.f;
                sp += adjv[jt][q] * mh;
            }
        }
        sp += __shfl_xor(sp, 16);
        sp += __shfl_xor(sp, 32);
        if (ln < 16) sS[w][ht * 16 + c] = sp;
    }
    if (ln == 0) sAs[w] = asum;
    __syncthreads();
    Sp[bx * cH + t] = sS[0][t] + sS[1][t] + sS[2][t] + sS[3][t];
    if (t == 0) AsumP[bx] = sAs[0] + sAs[1] + sAs[2] + sAs[3];
}

// ---- RT=4 rows, 1024 threads, k-split phases: matvec+update+LN+projections
__global__ __launch_bounds__(1024) void kU(const float* __restrict__ x_in,
                                           float* __restrict__ x_out,
                                           const float* __restrict__ Sp,
                                           const float* __restrict__ AsumP,
                                           const float* __restrict__ mw2,
                                           const float* __restrict__ mb2,
                                           const float* __restrict__ uw1,
                                           const float* __restrict__ ub1,
                                           const float* __restrict__ uw2,
                                           const float* __restrict__ ub2,
                                           const float* __restrict__ lng,
                                           const float* __restrict__ lnb,
                                           float* __restrict__ out,
                                           const float* __restrict__ ew1,
                                           const float* __restrict__ eb1,
                                           const float* __restrict__ mw1,
                                           const float* __restrict__ mb1,
                                           const float* __restrict__ bs2,
                                           float* __restrict__ P1,
                                           float* __restrict__ P2,
                                           float* __restrict__ P3,
                                           int l, int last) {
    __shared__ float sS[RT][cH];
    __shared__ float uin[RT][cH];
    __shared__ float uh[RT][cH];
    __shared__ float ph4[4][RT][cH];
    __shared__ float pm8[8][RT][cD];
    __shared__ float yb[RT][cD];
    __shared__ float xs[RT][cD];
    __shared__ float atots[RT];
    __shared__ float rs1h[RT][2], rs2h[RT][2];
    int r0 = blockIdx.x * RT, t = threadIdx.x;

    // phase 1: gather JS partial s-vectors, adj sums, x rows
    {
        int r = t >> 8, k = t & 255;
        float v = 0.f;
#pragma unroll
        for (int q = 0; q < JS; ++q) v += Sp[(JS * (r0 + r) + q) * cH + k];
        sS[r][k] = v;
    }
    if (t < RT) {
        float v = 0.f;
#pragma unroll
        for (int q = 0; q < JS; ++q) v += AsumP[JS * (r0 + t) + q];
        atots[t] = v;
    }
    if (t < 512) {
        int r = t >> 7, d = t & 127;
        uin[r][d] = x_in[(r0 + r) * cD + d];
    }
    __syncthreads();

    // phase 2: msg partials (K=256, 8-way split -> 32 iters)
    {
        int c = t & 127, kc = t >> 7;
        const float* mw2l = mw2 + l * cH * cD;
        float a[RT];
#pragma unroll
        for (int r = 0; r < RT; ++r) a[r] = 0.f;
        for (int k = kc * 32; k < kc * 32 + 32; ++k) {
            float w = mw2l[k * cD + c];
#pragma unroll
            for (int r = 0; r < RT; ++r) a[r] += sS[r][k] * w;
        }
#pragma unroll
        for (int r = 0; r < RT; ++r) pm8[kc][r][c] = a[r];
    }
    __syncthreads();
    if (t < 512) {
        int r = t >> 7, c = t & 127;
        float m = atots[r] * mb2[l * cD + c];
#pragma unroll
        for (int kc = 0; kc < 8; ++kc) m += pm8[kc][r][c];
        uin[r][cD + c] = m;
    }
    __syncthreads();

    // phase 3: uw1 partials (K=256, 4-way split -> 64 iters, N=256)
    {
        int col = t & 255, kc = t >> 8;
        const float* uw1l = uw1 + l * cH * cH;
        float a[RT];
#pragma unroll
        for (int r = 0; r < RT; ++r) a[r] = 0.f;
        for (int k = kc * 64; k < kc * 64 + 64; ++k) {
            float w = uw1l[k * cH + col];
#pragma unroll
            for (int r = 0; r < RT; ++r) a[r] += uin[r][k] * w;
        }
#pragma unroll
        for (int r = 0; r < RT; ++r) ph4[kc][r][col] = a[r];
    }
    __syncthreads();
    {
        int r = t >> 8, col = t & 255;
        float v = ub1[l * cH + col];
#pragma unroll
        for (int kc = 0; kc < 4; ++kc) v += ph4[kc][r][col];
        uh[r][col] = v > 0.f ? v : 0.f;
    }
    __syncthreads();

    // phase 4: uw2 partials (K=256, 8-way split -> 32 iters, N=128)
    {
        int c = t & 127, kc = t >> 7;
        const float* uw2l = uw2 + l * cH * cD;
        float a[RT];
#pragma unroll
        for (int r = 0; r < RT; ++r) a[r] = 0.f;
        for (int k = kc * 32; k < kc * 32 + 32; ++k) {
            float w = uw2l[k * cD + c];
#pragma unroll
            for (int r = 0; r < RT; ++r) a[r] += uh[r][k] * w;
        }
#pragma unroll
        for (int r = 0; r < RT; ++r) pm8[kc][r][c] = a[r];
    }
    __syncthreads();
    if (t < 512) {
        int r = t >> 7, c = t & 127;
        float v = uin[r][c] + ub2[l * cD + c];
#pragma unroll
        for (int kc = 0; kc < 8; ++kc) v += pm8[kc][r][c];
        yb[r][c] = v;
    }
    __syncthreads();

    // LayerNorm: rows r = t>>7 (two waves per row), q = t&127
    if (t < 512) {
        int r = t >> 7, q = t & 127;
        float y = yb[r][q];
        float s1 = y, s2 = y * y;
#pragma unroll
        for (int o = 1; o < 64; o <<= 1) { s1 += __shfl_xor(s1, o); s2 += __shfl_xor(s2, o); }
        if ((t & 63) == 0) { rs1h[r][q >> 6] = s1; rs2h[r][q >> 6] = s2; }
    }
    __syncthreads();
    if (t < 512) {
        int r = t >> 7, q = t & 127;
        float tot = rs1h[r][0] + rs1h[r][1];
        float tq  = rs2h[r][0] + rs2h[r][1];
        float mu  = tot * (1.f / cD);
        float var = tq * (1.f / cD) - mu * mu;
        float inv = rsqrtf(var + LN_EPSF);
        float res = (yb[r][q] - mu) * inv * lng[l * cD + q] + lnb[l * cD + q];
        x_out[(r0 + r) * cD + q] = res;
        xs[r][q] = res;
        if (last) out[(r0 + r) * cD + q] = res;
    }
    if (last) return;
    __syncthreads();

    // phase 5: next layer's projections
    proj_1024(xs, ph4, pm8, r0, t, ew1, eb1, mw1, mb1, bs2, P1, P2, P3, l + 1);
}

extern "C" void kernel_launch(void* const* d_in, const int* in_sizes, int n_in,
                              void* d_out, int out_size, void* d_ws, size_t ws_size,
                              hipStream_t stream) {
    (void)in_sizes; (void)n_in; (void)out_size; (void)ws_size;
    const float* nf  = (const float*)d_in[0];
    const float* adj = (const float*)d_in[1];
    const float* ew1 = (const float*)d_in[2];
    const float* eb1 = (const float*)d_in[3];
    const float* ew2 = (const float*)d_in[4];
    const float* eb2 = (const float*)d_in[5];
    const float* mw1 = (const float*)d_in[6];
    const float* mb1 = (const float*)d_in[7];
    const float* mw2 = (const float*)d_in[8];
    const float* mb2 = (const float*)d_in[9];
    const float* uw1 = (const float*)d_in[10];
    const float* ub1 = (const float*)d_in[11];
    const float* uw2 = (const float*)d_in[12];
    const float* ub2 = (const float*)d_in[13];
    const float* lng = (const float*)d_in[14];
    const float* lnb = (const float*)d_in[15];
    float* out = (float*)d_out;

    float* xbuf  = (float*)d_ws;                 // B*N*D
    float* P1    = xbuf + cB * cN * cD;          // B*N*E
    float* P2    = P1   + cB * cN * cE;          // B*N*E
    float* P3    = P2   + cB * cN * cE;          // B*N*2D
    float* Sp    = P3   + cB * cN * cH;          // JS*B*N*2D (partial s, per j-half)
    float* AsumP = Sp   + JS * cB * cN * cH;     // JS*B*N
    float* BS2   = AsumP + JS * cB * cN;         // L*2D
    ushort* W2f  = (ushort*)(BS2 + cL * cH);     // L*E*2D bf16 (frag-major)

    kW<<<cL * 8, 256, 0, stream>>>(ew2, eb2, mw1, W2f, BS2);
    kP<<<cB * cN / RT, 1024, 0, stream>>>(nf, ew1, eb1, mw1, mb1, BS2, P1, P2, P3);
    for (int l = 0; l < cL; ++l) {
        kB<<<cB * cN * JS, 256, 0, stream>>>(P1, P2, P3, adj, W2f, Sp, AsumP, l);
        kU<<<cB * cN / RT, 1024, 0, stream>>>((l == 0) ? nf : xbuf, xbuf, Sp, AsumP,
                                              mw2, mb2, uw1, ub1, uw2, ub2, lng, lnb, out,
                                              ew1, eb1, mw1, mb1, BS2, P1, P2, P3,
                                              l, l == cL - 1);
    }
}

// Round 16
// 101.915 us; speedup vs baseline: 1.2302x; 1.2302x over previous
//
#include <hip/hip_runtime.h>
#include <hip/hip_bf16.h>

// GraphFusion: 3-layer GNN, B=4 N=256 D=128 E=64.
// Exact algebra:
//   eh   = relu(P1_i + P2_j)            P1 = x@w_top + eb1, P2 = x@w_bot
//   mh   = relu(P3_i + eh@W2)           W2 = ew2@mw_bot (precomputed, bf16 frag-major)
//                                       P3 = x@mw_top + mb1 + eb2@mw_bot
//   s_i  = sum_j adj_ij * mh_ij         (fold adjacency BEFORE mw2)
//   msg_i= s_i@mw2 + (sum_j adj_ij)*mb2
//   x    = LN(x + u2(relu(u1(cat(x,msg)))))
// kL: FUSED per-layer kernel (kB+kU merged). 256 blocks x 1024 thr; wave w =
//     (row w>>2, j-quarter w&3) computes the MFMA s-partials; same block then
//     runs matvec+update+LN+next-layer proj. Kills Sp/AsumP round-trip + 3
//     dispatches/graph. P1/P2/P3 ping-pong buffers (intra-kernel read/write race).
// Dead ends (replication-confirmed): JS=4, unroll-8 caps, P3-as-C-init, W2f-LDS.

constexpr int cB = 4, cN = 256, cD = 128, cE = 64, cL = 3, cH = 256; // cH = 2D
constexpr int RT = 4;                       // rows per kL/kP block
#define LN_EPSF 1e-5f

typedef __attribute__((ext_vector_type(8))) short bf8;
typedef __attribute__((ext_vector_type(4))) float f4;

__device__ __forceinline__ ushort f2bf(float f) {  // RNE float->bf16 bits
    uint u = __float_as_uint(f);
    u += 0x7FFFu + ((u >> 16) & 1u);
    return (ushort)(u >> 16);
}

// ---- W2f[l] in MFMA B-fragment-major bf16
__global__ __launch_bounds__(256) void kW(const float* __restrict__ ew2,
                                          const float* __restrict__ eb2,
                                          const float* __restrict__ mw1,
                                          ushort* __restrict__ W2f,
                                          float* __restrict__ BS2) {
    int bx = blockIdx.x, l = bx >> 3, f0 = (bx & 7) * 8;
    int h = threadIdx.x;
    const float* ew2l = ew2 + l * cE * cE;
    const float* eb2l = eb2 + l * cE;
    const float* mbot = mw1 + l * (cD + cE) * cH + cD * cH;
    float acc[8];
#pragma unroll
    for (int f = 0; f < 8; ++f) acc[f] = 0.f;
    float bacc = 0.f;
    for (int e = 0; e < cE; ++e) {
        float m = mbot[e * cH + h];
        if (f0 == 0) bacc += eb2l[e] * m;
#pragma unroll
        for (int f = 0; f < 8; ++f) acc[f] += ew2l[(f0 + f) * cE + e] * m;
    }
    ushort* W2fl = W2f + l * cE * cH;
    int ht = h >> 4, hc = h & 15;
#pragma unroll
    for (int f = 0; f < 8; ++f) {
        int ff = f0 + f;
        int kc = ff >> 5, lg = (ff >> 3) & 3, e = ff & 7;
        W2fl[((ht * 2 + kc) * 64 + lg * 16 + hc) * 8 + e] = f2bf(acc[f]);
    }
    if (f0 == 0) BS2[l * cH + h] = bacc;
}

// ---- projection phase, 1024-thread k-split (shared by kP and kL)
__device__ __forceinline__ void proj_1024(const float (*xs)[cD],
                                          float (*ph4)[RT][cH],
                                          float (*pm8)[RT][cD],
                                          int r0, int t,
                                          const float* __restrict__ ew1,
                                          const float* __restrict__ eb1,
                                          const float* __restrict__ mw1,
                                          const float* __restrict__ mb1,
                                          const float* __restrict__ bs2,
                                          float* __restrict__ P1,
                                          float* __restrict__ P2,
                                          float* __restrict__ P3, int nl) {
    {
        int col = t & 255, kc = t >> 8;
        const float* mw1n = mw1 + nl * (cD + cE) * cH;
        float a[RT];
#pragma unroll
        for (int r = 0; r < RT; ++r) a[r] = 0.f;
        for (int k = kc * 32; k < kc * 32 + 32; ++k) {
            float w = mw1n[k * cH + col];
#pragma unroll
            for (int r = 0; r < RT; ++r) a[r] += xs[r][k] * w;
        }
#pragma unroll
        for (int r = 0; r < RT; ++r) ph4[kc][r][col] = a[r];
    }
    {
        int cc = t & 127, kc = t >> 7;
        int which = cc >> 6, e = cc & 63;
        const float* ew1n = ew1 + nl * 2 * cD * cE + which * cD * cE;
        float a[RT];
#pragma unroll
        for (int r = 0; r < RT; ++r) a[r] = 0.f;
        for (int k = kc * 16; k < kc * 16 + 16; ++k) {
            float w = ew1n[k * cE + e];
#pragma unroll
            for (int r = 0; r < RT; ++r) a[r] += xs[r][k] * w;
        }
#pragma unroll
        for (int r = 0; r < RT; ++r) pm8[kc][r][cc] = a[r];
    }
    __syncthreads();
    {
        int r = t >> 8, col = t & 255;
        float v = mb1[nl * cH + col] + bs2[nl * cH + col];
#pragma unroll
        for (int kc = 0; kc < 4; ++kc) v += ph4[kc][r][col];
        P3[(r0 + r) * cH + col] = v;
    }
    if (t < 512) {
        int r = t >> 7, cc = t & 127, which = cc >> 6, e = cc & 63;
        float v = which ? 0.f : eb1[nl * cE + e];
#pragma unroll
        for (int kc = 0; kc < 8; ++kc) v += pm8[kc][r][cc];
        (which ? P2 : P1)[(r0 + r) * cE + e] = v;
    }
}

// ---- layer-0 projections, grid = B*N/RT, 1024 threads
__global__ __launch_bounds__(1024) void kP(const float* __restrict__ x,
                                           const float* __restrict__ ew1,
                                           const float* __restrict__ eb1,
                                           const float* __restrict__ mw1,
                                           const float* __restrict__ mb1,
                                           const float* __restrict__ bs2,
                                           float* __restrict__ P1,
                                           float* __restrict__ P2,
                                           float* __restrict__ P3) {
    __shared__ float xs[RT][cD];
    __shared__ float ph4[4][RT][cH];
    __shared__ float pm8[8][RT][cD];
    int r0 = blockIdx.x * RT, t = threadIdx.x;
    if (t < 512) {
        int r = t >> 7, d = t & 127;
        xs[r][d] = x[(r0 + r) * cD + d];
    }
    __syncthreads();
    proj_1024(xs, ph4, pm8, r0, t, ew1, eb1, mw1, mb1, bs2, P1, P2, P3, 0);
}

// ---- FUSED layer kernel: GEMM s-vectors + matvec + update + LN + projections
// block = RT=4 rows, 1024 threads (16 waves). Wave w: row rw=w>>2, j-quarter qd=w&3.
__global__ __launch_bounds__(1024) void kL(const float* __restrict__ x_in,
                                           float* __restrict__ x_out,
                                           const float* __restrict__ P1,
                                           const float* __restrict__ P2,
                                           const float* __restrict__ P3g,
                                           const float* __restrict__ adj,
                                           const ushort* __restrict__ W2f,
                                           const float* __restrict__ mw2,
                                           const float* __restrict__ mb2,
                                           const float* __restrict__ uw1,
                                           const float* __restrict__ ub1,
                                           const float* __restrict__ uw2,
                                           const float* __restrict__ ub2,
                                           const float* __restrict__ lng,
                                           const float* __restrict__ lnb,
                                           float* __restrict__ out,
                                           const float* __restrict__ ew1,
                                           const float* __restrict__ eb1,
                                           const float* __restrict__ mw1,
                                           const float* __restrict__ mb1,
                                           const float* __restrict__ bs2,
                                           float* __restrict__ P1o,
                                           float* __restrict__ P2o,
                                           float* __restrict__ P3o,
                                           int l, int last) {
    __shared__ float sP3[RT][cH];          // 4KB (GEMM phase)
    __shared__ float sSw[16][cH];          // 16KB: GEMM partials; REUSED as ph4
    __shared__ float pm8[8][RT][cD];       // 16KB
    __shared__ float sS[RT][cH];           // 4KB
    __shared__ float uin[RT][cH];          // 4KB
    __shared__ float uh[RT][cH];           // 4KB
    __shared__ float yb[RT][cD];           // 2KB
    __shared__ float xs[RT][cD];           // 2KB
    __shared__ float sAsw[16];
    __shared__ float atots[RT];
    __shared__ float rs1h[RT][2], rs2h[RT][2];

    int bx = blockIdx.x, t = threadIdx.x;
    int r0 = bx * RT;
    int w = t >> 6, ln = t & 63, g = ln >> 4, c = ln & 15;
    int rw = w >> 2, qd = w & 3;
    int bn = r0 + rw;                       // this wave's output row
    int b  = bn >> 8;
    int jw = qd * 64;

    sP3[t >> 8][t & 255] = P3g[(r0 + (t >> 8)) * cH + (t & 255)];

    // adjacency for this wave's 64 j's
    const float* adjr = adj + bn * cN + jw;
    float adjv[4][4];
    float asum = 0.f;
#pragma unroll
    for (int jt = 0; jt < 4; ++jt)
#pragma unroll
        for (int q = 0; q < 4; ++q) {
            float a = adjr[jt * 16 + g * 4 + q];
            adjv[jt][q] = a;
            asum += a;
        }
    asum += __shfl_xor(asum, 16);
    asum += __shfl_xor(asum, 32);

    // P1 fragment pieces
    const float* p1p = P1 + bn * cE;
    f4 p1lo[2], p1hi[2];
#pragma unroll
    for (int kc = 0; kc < 2; ++kc) {
        p1lo[kc] = *(const f4*)(p1p + kc * 32 + g * 8);
        p1hi[kc] = *(const f4*)(p1p + kc * 32 + g * 8 + 4);
    }

    // A fragments: af[jt][kc], 4 j-tiles of 16
    bf8 af[4][2];
#pragma unroll
    for (int jt = 0; jt < 4; ++jt) {
        const float* p2r = P2 + (b * cN + jw + jt * 16 + c) * cE;
#pragma unroll
        for (int kc = 0; kc < 2; ++kc) {
            f4 v0 = *(const f4*)(p2r + kc * 32 + g * 8);
            f4 v1 = *(const f4*)(p2r + kc * 32 + g * 8 + 4);
            bf8 a;
#pragma unroll
            for (int e = 0; e < 4; ++e) {
                float x0 = v0[e] + p1lo[kc][e]; x0 = x0 > 0.f ? x0 : 0.f;
                float x1 = v1[e] + p1hi[kc][e]; x1 = x1 > 0.f ? x1 : 0.f;
                a[e]     = (short)f2bf(x0);
                a[e + 4] = (short)f2bf(x1);
            }
            af[jt][kc] = a;
        }
    }
    __syncthreads();   // sP3 ready

    // GEMM phase: 16 ht x 4 jt x 2 MFMA
    {
        const ushort* W2l = W2f + l * cE * cH;
        bf8 nb0 = *(const bf8*)(W2l + (0 * 64 + ln) * 8);
        bf8 nb1 = *(const bf8*)(W2l + (1 * 64 + ln) * 8);
        for (int ht = 0; ht < 16; ++ht) {
            bf8 b0 = nb0, b1 = nb1;
            if (ht < 15) {
                nb0 = *(const bf8*)(W2l + (((ht + 1) * 2 + 0) * 64 + ln) * 8);
                nb1 = *(const bf8*)(W2l + (((ht + 1) * 2 + 1) * 64 + ln) * 8);
            }
            float p3v = sP3[rw][ht * 16 + c];
            float sp = 0.f;
#pragma unroll
            for (int jt = 0; jt < 4; ++jt) {
                f4 acc = {0.f, 0.f, 0.f, 0.f};
                acc = __builtin_amdgcn_mfma_f32_16x16x32_bf16(af[jt][0], b0, acc, 0, 0, 0);
                acc = __builtin_amdgcn_mfma_f32_16x16x32_bf16(af[jt][1], b1, acc, 0, 0, 0);
#pragma unroll
                for (int q = 0; q < 4; ++q) {  // D[row=jt*16+g*4+q][col=ht*16+c]
                    float mh = p3v + acc[q];
                    mh = mh > 0.f ? mh : 0.f;
                    sp += adjv[jt][q] * mh;
                }
            }
            sp += __shfl_xor(sp, 16);
            sp += __shfl_xor(sp, 32);
            if (ln < 16) sSw[w][ht * 16 + c] = sp;
        }
    }
    if (ln == 0) sAsw[w] = asum;
    __syncthreads();

    // gather s-vectors + adj totals + x rows
    {
        int r = t >> 8, k = t & 255;
        sS[r][k] = sSw[4 * r + 0][k] + sSw[4 * r + 1][k]
                 + sSw[4 * r + 2][k] + sSw[4 * r + 3][k];
    }
    if (t < RT)
        atots[t] = sAsw[4 * t] + sAsw[4 * t + 1] + sAsw[4 * t + 2] + sAsw[4 * t + 3];
    if (t < 512) {
        int r = t >> 7, d = t & 127;
        uin[r][d] = x_in[(r0 + r) * cD + d];
    }
    __syncthreads();

    // phase 2: msg partials (K=256, 8-way split)
    {
        int cc = t & 127, kc = t >> 7;
        const float* mw2l = mw2 + l * cH * cD;
        float a[RT];
#pragma unroll
        for (int r = 0; r < RT; ++r) a[r] = 0.f;
        for (int k = kc * 32; k < kc * 32 + 32; ++k) {
            float wv = mw2l[k * cD + cc];
#pragma unroll
            for (int r = 0; r < RT; ++r) a[r] += sS[r][k] * wv;
        }
#pragma unroll
        for (int r = 0; r < RT; ++r) pm8[kc][r][cc] = a[r];
    }
    __syncthreads();
    if (t < 512) {
        int r = t >> 7, cc = t & 127;
        float m = atots[r] * mb2[l * cD + cc];
#pragma unroll
        for (int kc = 0; kc < 8; ++kc) m += pm8[kc][r][cc];
        uin[r][cD + cc] = m;
    }
    __syncthreads();

    // phase 3: uw1 partials (4-way split) -> sSw reused as ph4[kc][r] = sSw[kc*RT+r]
    {
        int col = t & 255, kc = t >> 8;
        const float* uw1l = uw1 + l * cH * cH;
        float a[RT];
#pragma unroll
        for (int r = 0; r < RT; ++r) a[r] = 0.f;
        for (int k = kc * 64; k < kc * 64 + 64; ++k) {
            float wv = uw1l[k * cH + col];
#pragma unroll
            for (int r = 0; r < RT; ++r) a[r] += uin[r][k] * wv;
        }
#pragma unroll
        for (int r = 0; r < RT; ++r) sSw[kc * RT + r][col] = a[r];
    }
    __syncthreads();
    {
        int r = t >> 8, col = t & 255;
        float v = ub1[l * cH + col];
#pragma unroll
        for (int kc = 0; kc < 4; ++kc) v += sSw[kc * RT + r][col];
        uh[r][col] = v > 0.f ? v : 0.f;
    }
    __syncthreads();

    // phase 4: uw2 partials (8-way split)
    {
        int cc = t & 127, kc = t >> 7;
        const float* uw2l = uw2 + l * cH * cD;
        float a[RT];
#pragma unroll
        for (int r = 0; r < RT; ++r) a[r] = 0.f;
        for (int k = kc * 32; k < kc * 32 + 32; ++k) {
            float wv = uw2l[k * cD + cc];
#pragma unroll
            for (int r = 0; r < RT; ++r) a[r] += uh[r][k] * wv;
        }
#pragma unroll
        for (int r = 0; r < RT; ++r) pm8[kc][r][cc] = a[r];
    }
    __syncthreads();
    if (t < 512) {
        int r = t >> 7, cc = t & 127;
        float v = uin[r][cc] + ub2[l * cD + cc];
#pragma unroll
        for (int kc = 0; kc < 8; ++kc) v += pm8[kc][r][cc];
        yb[r][cc] = v;
    }
    __syncthreads();

    // LayerNorm
    if (t < 512) {
        int r = t >> 7, q = t & 127;
        float y = yb[r][q];
        float s1 = y, s2 = y * y;
#pragma unroll
        for (int o = 1; o < 64; o <<= 1) { s1 += __shfl_xor(s1, o); s2 += __shfl_xor(s2, o); }
        if ((t & 63) == 0) { rs1h[r][q >> 6] = s1; rs2h[r][q >> 6] = s2; }
    }
    __syncthreads();
    if (t < 512) {
        int r = t >> 7, q = t & 127;
        float tot = rs1h[r][0] + rs1h[r][1];
        float tq  = rs2h[r][0] + rs2h[r][1];
        float mu  = tot * (1.f / cD);
        float var = tq * (1.f / cD) - mu * mu;
        float inv = rsqrtf(var + LN_EPSF);
        float res = (yb[r][q] - mu) * inv * lng[l * cD + q] + lnb[l * cD + q];
        x_out[(r0 + r) * cD + q] = res;
        xs[r][q] = res;
        if (last) out[(r0 + r) * cD + q] = res;
    }
    if (last) return;
    __syncthreads();

    // projections for next layer (ping-pong buffers; sSw reused as ph4)
    proj_1024(xs, reinterpret_cast<float (*)[RT][cH]>(&sSw[0][0]), pm8,
              r0, t, ew1, eb1, mw1, mb1, bs2, P1o, P2o, P3o, l + 1);
}

extern "C" void kernel_launch(void* const* d_in, const int* in_sizes, int n_in,
                              void* d_out, int out_size, void* d_ws, size_t ws_size,
                              hipStream_t stream) {
    (void)in_sizes; (void)n_in; (void)out_size; (void)ws_size;
    const float* nf  = (const float*)d_in[0];
    const float* adj = (const float*)d_in[1];
    const float* ew1 = (const float*)d_in[2];
    const float* eb1 = (const float*)d_in[3];
    const float* ew2 = (const float*)d_in[4];
    const float* eb2 = (const float*)d_in[5];
    const float* mw1 = (const float*)d_in[6];
    const float* mb1 = (const float*)d_in[7];
    const float* mw2 = (const float*)d_in[8];
    const float* mb2 = (const float*)d_in[9];
    const float* uw1 = (const float*)d_in[10];
    const float* ub1 = (const float*)d_in[11];
    const float* uw2 = (const float*)d_in[12];
    const float* ub2 = (const float*)d_in[13];
    const float* lng = (const float*)d_in[14];
    const float* lnb = (const float*)d_in[15];
    float* out = (float*)d_out;

    float* xbuf  = (float*)d_ws;                 // B*N*D
    float* P1a   = xbuf + cB * cN * cD;          // ping-pong set A
    float* P2a   = P1a  + cB * cN * cE;
    float* P3a   = P2a  + cB * cN * cE;
    float* P1b   = P3a  + cB * cN * cH;          // ping-pong set B
    float* P2b   = P1b  + cB * cN * cE;
    float* P3b   = P2b  + cB * cN * cE;
    float* BS2   = P3b  + cB * cN * cH;          // L*2D
    ushort* W2f  = (ushort*)(BS2 + cL * cH);     // L*E*2D bf16 (frag-major)

    float* P1s[2] = {P1a, P1b};
    float* P2s[2] = {P2a, P2b};
    float* P3s[2] = {P3a, P3b};

    kW<<<cL * 8, 256, 0, stream>>>(ew2, eb2, mw1, W2f, BS2);
    kP<<<cB * cN / RT, 1024, 0, stream>>>(nf, ew1, eb1, mw1, mb1, BS2, P1a, P2a, P3a);
    for (int l = 0; l < cL; ++l) {
        int pi = l & 1, po = (l + 1) & 1;
        kL<<<cB * cN / RT, 1024, 0, stream>>>((l == 0) ? nf : xbuf, xbuf,
                                              P1s[pi], P2s[pi], P3s[pi], adj, W2f,
                                              mw2, mb2, uw1, ub1, uw2, ub2, lng, lnb,
                                              out, ew1, eb1, mw1, mb1, BS2,
                                              P1s[po], P2s[po], P3s[po],
                                              l, l == cL - 1);
    }
}